// Round 3
// baseline (775.972 us; speedup 1.0000x reference)
//
#include <hip/hip_runtime.h>
#include <hip/hip_bf16.h>

#define Bb 64
#define Tt 20
#define Ee 512
#define Vv 32000

typedef __hip_bfloat16 bf16;
typedef __attribute__((ext_vector_type(8))) short bf16x8;
typedef __attribute__((ext_vector_type(4))) float f32x4;

__device__ __forceinline__ float bf2f(bf16 x) { return __bfloat162float(x); }
__device__ __forceinline__ bf16 f2bf(float x) { return __float2bfloat16(x); }

// ---------------------------------------------------------------------------
// Kernel 0: fp32 -> bf16 weight conversion (W_ih / W_hh), once per call.
// Each thread converts 4 floats (float4 load, ushort4 store).
// ---------------------------------------------------------------------------
__global__ void convert_w(const float* __restrict__ src, bf16* __restrict__ dst) {
  int i = blockIdx.x * blockDim.x + threadIdx.x;
  float4 v = ((const float4*)src)[i];
  union { ushort4 u; bf16 h[4]; } pk;
  pk.h[0] = f2bf(v.x); pk.h[1] = f2bf(v.y); pk.h[2] = f2bf(v.z); pk.h[3] = f2bf(v.w);
  ((ushort4*)dst)[i] = pk.u;
}

// ---------------------------------------------------------------------------
// Kernel 1: embedding gather (fp32 -> bf16) + state init.
// grid = B*T blocks, 128 threads (4 elements each).
//  - emb[b,t,:]  = bf16(W_emb[captions[b,t], :])
//  - seq[b,0,:]  = emb[b,0,:]
//  - zbuf[b,:]   = 0          (h_0, bf16)
//  - c[b,:]      = features[b,:]   (fp32 copy)
// ---------------------------------------------------------------------------
__global__ void embed_init(const int* __restrict__ caps, const float* __restrict__ Wemb,
                           const float* __restrict__ feats, bf16* __restrict__ emb,
                           bf16* __restrict__ seq, bf16* __restrict__ zbuf,
                           float* __restrict__ c) {
  int row = blockIdx.x;            // b*T + t
  int b = row / Tt, t = row % Tt;
  int tid = threadIdx.x;           // 0..127
  int tok = caps[row];
  float4 v = ((const float4*)(Wemb + (size_t)tok * Ee))[tid];
  union { ushort4 u; bf16 h[4]; } pk;
  pk.h[0] = f2bf(v.x); pk.h[1] = f2bf(v.y); pk.h[2] = f2bf(v.z); pk.h[3] = f2bf(v.w);
  ((ushort4*)(emb + (size_t)row * Ee))[tid] = pk.u;
  if (t == 0) ((ushort4*)(seq + (size_t)row * Ee))[tid] = pk.u;   // row == b*T
  if (t == 1) {
    ushort4 z; z.x = z.y = z.z = z.w = 0;
    ((ushort4*)(zbuf + (size_t)b * Ee))[tid] = z;
    ((float4*)(c + (size_t)b * Ee))[tid] = ((const float4*)(feats + (size_t)b * Ee))[tid];
  }
}

// ---------------------------------------------------------------------------
// Kernel 2: one LSTM step (fused gates GEMM + pointwise).
// grid = 32 WGs (j-tile of 16), 256 threads = 4 waves; wave g = gate g.
// x, h, W in bf16 (pre-converted); biases/cell fp32; h_t -> seq (bf16).
// ---------------------------------------------------------------------------
__global__ __launch_bounds__(256) void lstm_step(
    const bf16* __restrict__ xb,                 // x row b at xb + b*T*E
    const bf16* __restrict__ hb, long hstride,   // h row b at hb + b*hstride
    float* __restrict__ c,
    const bf16* __restrict__ Wih, const bf16* __restrict__ Whh,
    const float* __restrict__ bih, const float* __restrict__ bhh,
    bf16* __restrict__ seqout)                   // h_t row b at seqout + b*T*E
{
  const long XS = (long)Tt * Ee;
  int tid = threadIdx.x;
  int g = tid >> 6;                 // wave id == gate id (0=i,1=f,2=g,3=o)
  int lane = tid & 63;
  int quad = lane >> 4, ln = lane & 15;
  int j0 = blockIdx.x * 16;

  const bf16* wri = Wih + (size_t)(g * Ee + j0 + ln) * Ee;
  const bf16* wrh = Whh + (size_t)(g * Ee + j0 + ln) * Ee;

  f32x4 zero = {0.f, 0.f, 0.f, 0.f};
  f32x4 acc[4];
#pragma unroll
  for (int mt = 0; mt < 4; ++mt) acc[mt] = zero;

  // x @ W_ih^T
#pragma unroll 4
  for (int kk = 0; kk < 16; ++kk) {
    int k = kk * 32 + quad * 8;
    bf16x8 bfrag = *(const bf16x8*)(wri + k);
#pragma unroll
    for (int mt = 0; mt < 4; ++mt) {
      bf16x8 afrag = *(const bf16x8*)(xb + (size_t)(mt * 16 + ln) * XS + k);
      acc[mt] = __builtin_amdgcn_mfma_f32_16x16x32_bf16(afrag, bfrag, acc[mt], 0, 0, 0);
    }
  }
  // h @ W_hh^T
#pragma unroll 4
  for (int kk = 0; kk < 16; ++kk) {
    int k = kk * 32 + quad * 8;
    bf16x8 bfrag = *(const bf16x8*)(wrh + k);
#pragma unroll
    for (int mt = 0; mt < 4; ++mt) {
      bf16x8 afrag = *(const bf16x8*)(hb + (size_t)(mt * 16 + ln) * hstride + k);
      acc[mt] = __builtin_amdgcn_mfma_f32_16x16x32_bf16(afrag, bfrag, acc[mt], 0, 0, 0);
    }
  }

  __shared__ float gsm[4][64][16];   // [gate][b][j]
#pragma unroll
  for (int mt = 0; mt < 4; ++mt)
#pragma unroll
    for (int r = 0; r < 4; ++r)
      gsm[g][mt * 16 + quad * 4 + r][ln] = acc[mt][r];
  __syncthreads();

  // pointwise: 1024 (b,j) pairs, 4 per thread
#pragma unroll
  for (int it = 0; it < 4; ++it) {
    int p = tid + it * 256;
    int b = p >> 4, jl = p & 15;
    int jj = j0 + jl;
    float iv = gsm[0][b][jl] + bih[jj]          + bhh[jj];
    float fv = gsm[1][b][jl] + bih[Ee + jj]     + bhh[Ee + jj];
    float gv = gsm[2][b][jl] + bih[2 * Ee + jj] + bhh[2 * Ee + jj];
    float ov = gsm[3][b][jl] + bih[3 * Ee + jj] + bhh[3 * Ee + jj];
    iv = 1.f / (1.f + __expf(-iv));
    fv = 1.f / (1.f + __expf(-fv));
    ov = 1.f / (1.f + __expf(-ov));
    gv = tanhf(gv);
    float cv = fv * c[b * Ee + jj] + iv * gv;
    c[b * Ee + jj] = cv;
    float hv = ov * tanhf(cv);
    seqout[(size_t)b * XS + jj] = f2bf(hv);
  }
}

// ---------------------------------------------------------------------------
// Kernel 3: logits = seq[1280,512](bf16) @ W_out[32000,512](fp32)^T + b_out.
// 128x128 tile, BK=64, register staging; W_out converted fp32->bf16 during
// staging; fp32 epilogue/output. M=10*128, N=250*128, K=8*64 -> no tails.
// ---------------------------------------------------------------------------
#define BM 128
#define BN 128
#define BK 64

__global__ __launch_bounds__(256) void out_gemm(const bf16* __restrict__ A,    // [1280,512] bf16
                                                const float* __restrict__ Bw,  // [32000,512] fp32
                                                const float* __restrict__ bias,
                                                float* __restrict__ Cb) {
  __shared__ __align__(16) bf16 As[BM * BK];   // 16 KB
  __shared__ __align__(16) bf16 Bs[BN * BK];   // 16 KB
  int tid = threadIdx.x;
  int lane = tid & 63;
  int quad = lane >> 4, ln = lane & 15;
  int wid = tid >> 6;
  int wm = wid & 1, wn = wid >> 1;
  int m0 = blockIdx.y * BM, n0 = blockIdx.x * BN;

  f32x4 zero = {0.f, 0.f, 0.f, 0.f};
  f32x4 acc[4][4];
#pragma unroll
  for (int mt = 0; mt < 4; ++mt)
#pragma unroll
    for (int nt = 0; nt < 4; ++nt) acc[mt][nt] = zero;

  for (int k0 = 0; k0 < Ee; k0 += BK) {
    uint4 avv[4];
    float4 bf0[4], bf1[4];
#pragma unroll
    for (int q = 0; q < 4; ++q) {
      int fb = (q * 256 + tid) * 16;   // byte offset within bf16 tile
      int row = fb >> 7;               // 128 B per row (64 bf16)
      int c8 = (fb & 127) >> 1;        // bf16 column start
      avv[q] = *(const uint4*)((const char*)A + ((size_t)(m0 + row) * Ee + k0) * 2 + (fb & 127));
      const float* src = Bw + (size_t)(n0 + row) * Ee + k0 + c8;
      bf0[q] = *(const float4*)(src);
      bf1[q] = *(const float4*)(src + 4);
    }
#pragma unroll
    for (int q = 0; q < 4; ++q) {
      int fb = (q * 256 + tid) * 16;
      *(uint4*)((char*)As + fb) = avv[q];
      union { uint4 u; bf16 h[8]; } pk;
      pk.h[0] = f2bf(bf0[q].x); pk.h[1] = f2bf(bf0[q].y);
      pk.h[2] = f2bf(bf0[q].z); pk.h[3] = f2bf(bf0[q].w);
      pk.h[4] = f2bf(bf1[q].x); pk.h[5] = f2bf(bf1[q].y);
      pk.h[6] = f2bf(bf1[q].z); pk.h[7] = f2bf(bf1[q].w);
      *(uint4*)((char*)Bs + fb) = pk.u;
    }
    __syncthreads();

#pragma unroll
    for (int kk = 0; kk < 2; ++kk) {
      int kb = (kk * 32 + quad * 8) * 2;
      bf16x8 af[4], bfv[4];
#pragma unroll
      for (int mt = 0; mt < 4; ++mt)
        af[mt] = *(const bf16x8*)((const char*)As + (wm * 64 + mt * 16 + ln) * 128 + kb);
#pragma unroll
      for (int nt = 0; nt < 4; ++nt)
        bfv[nt] = *(const bf16x8*)((const char*)Bs + (wn * 64 + nt * 16 + ln) * 128 + kb);
#pragma unroll
      for (int mt = 0; mt < 4; ++mt)
#pragma unroll
        for (int nt = 0; nt < 4; ++nt)
          acc[mt][nt] = __builtin_amdgcn_mfma_f32_16x16x32_bf16(af[mt], bfv[nt], acc[mt][nt], 0, 0, 0);
    }
    __syncthreads();
  }

  // epilogue: + bias, fp32 store. D: col = lane&15, row = quad*4 + reg.
  float bv[4];
#pragma unroll
  for (int nt = 0; nt < 4; ++nt)
    bv[nt] = bias[n0 + wn * 64 + nt * 16 + ln];
#pragma unroll
  for (int mt = 0; mt < 4; ++mt) {
#pragma unroll
    for (int nt = 0; nt < 4; ++nt) {
      int col = n0 + wn * 64 + nt * 16 + ln;
#pragma unroll
      for (int r = 0; r < 4; ++r) {
        int row = m0 + wm * 64 + mt * 16 + quad * 4 + r;
        Cb[(size_t)row * Vv + col] = acc[mt][nt][r] + bv[nt];
      }
    }
  }
}

// ---------------------------------------------------------------------------
extern "C" void kernel_launch(void* const* d_in, const int* in_sizes, int n_in,
                              void* d_out, int out_size, void* d_ws, size_t ws_size,
                              hipStream_t stream) {
  (void)in_sizes; (void)n_in; (void)out_size; (void)ws_size;
  const float* feats = (const float*)d_in[0];
  const int*   caps  = (const int*)d_in[1];
  const float* Wemb  = (const float*)d_in[2];
  const float* Wout  = (const float*)d_in[3];
  const float* bout  = (const float*)d_in[4];
  const float* Wih   = (const float*)d_in[5];
  const float* Whh   = (const float*)d_in[6];
  const float* bih   = (const float*)d_in[7];
  const float* bhh   = (const float*)d_in[8];
  float* out = (float*)d_out;

  // workspace layout (16B-aligned), ~7 MB total:
  bf16* emb    = (bf16*)d_ws;                         // [B,T,E]  1.31 MB
  bf16* seq    = emb  + (size_t)Bb * Tt * Ee;         // [B,T,E]  1.31 MB
  bf16* zbuf   = seq  + (size_t)Bb * Tt * Ee;         // [B,E]    64 KB (h_0=0)
  float* c     = (float*)(zbuf + (size_t)Bb * Ee);    // [B,E]    128 KB fp32
  bf16* Wih_b  = (bf16*)(c + (size_t)Bb * Ee);        // [4E,E]   2 MB
  bf16* Whh_b  = Wih_b + (size_t)4 * Ee * Ee;         // [4E,E]   2 MB

  const int WN4 = (4 * Ee * Ee) / 4;                  // float4s per weight matrix
  convert_w<<<WN4 / 256, 256, 0, stream>>>(Wih, Wih_b);
  convert_w<<<WN4 / 256, 256, 0, stream>>>(Whh, Whh_b);
  embed_init<<<Bb * Tt, 128, 0, stream>>>(caps, Wemb, feats, emb, seq, zbuf, c);

  for (int t = 1; t < Tt; ++t) {
    const bf16* xb = emb + (size_t)(t - 1) * Ee;                       // x_t = emb[:, t-1]
    const bf16* hb = (t == 1) ? zbuf : (seq + (size_t)(t - 1) * Ee);   // h_{t-1}
    long hstride = (t == 1) ? (long)Ee : (long)Tt * Ee;
    lstm_step<<<32, 256, 0, stream>>>(xb, hb, hstride, c, Wih_b, Whh_b, bih, bhh,
                                      seq + (size_t)t * Ee);
  }

  dim3 grid(Vv / BN, (Bb * Tt) / BM);   // 250 x 10
  out_gemm<<<grid, 256, 0, stream>>>(seq, Wout, bout, out);
}